// Round 1
// baseline (1886.038 us; speedup 1.0000x reference)
//
#include <hip/hip_runtime.h>
#include <math.h>

#define PP 40000
#define HDIM 200
#define WDIM 200
#define NEPS 1e-8f

// workspace layout (float offsets)
#define OFF_COM    0            // 15*PP
#define OFF_ENT    (15*PP)      // 15*PP
#define OFF_MASK   (30*PP)      // 12*PP
#define OFF_DEN    (42*PP)      // 12*PP
#define OFF_LOGITS (54*PP)      // 15*PP
#define OFF_U      (69*PP)      // 3*128*PP
#define MISC_FULL  (453*PP)
#define MISC_MIN   (69*PP)
// misc (uint slots): [0..11] min_ord, [12..23] max_ord, [24] count, [25..36] iszero

__device__ __forceinline__ unsigned f2ord(float f){
    unsigned u = __float_as_uint(f);
    return (u & 0x80000000u) ? ~u : (u | 0x80000000u);
}
__device__ __forceinline__ float ord2f(unsigned u){
    unsigned v = (u & 0x80000000u) ? (u & 0x7fffffffu) : ~u;
    return __uint_as_float(v);
}

__device__ __forceinline__ void tap_setup(int p, int* off, bool* val){
    int h = p / WDIM, w = p - h*WDIM;
#pragma unroll
    for (int ky=0;ky<3;ky++)
#pragma unroll
        for (int kx=0;kx<3;kx++){
            int t = ky*3+kx;
            int hh = h+ky-1, ww = w+kx-1;
            val[t] = (hh>=0)&&(hh<HDIM)&&(ww>=0)&&(ww<WDIM);
            off[t] = hh*WDIM+ww;
        }
}

__global__ void k_init(unsigned* misc){
    int t = threadIdx.x;
    if (t < 12) misc[t] = 0xFFFFFFFFu;        // min (sortable) = +inf
    else if (t < 25) misc[t] = 0u;            // max = -inf, count = 0
}

// compress conv3x3 (64->1) + relu, fused per-image min/max of raw nb values
__global__ __launch_bounds__(256) void k_conv(const float* __restrict__ bevs,
        const float* __restrict__ cw, const float* __restrict__ cb,
        float* __restrict__ com, unsigned* __restrict__ misc)
{
    __shared__ float wl[576];
    int img = blockIdx.y;          // 0..14 = bt*5+n
    int n = img % 5;
    for (int i = threadIdx.x; i < 576; i += 256) wl[i] = cw[i];
    __syncthreads();
    int p = blockIdx.x*256 + threadIdx.x;
    float vmin = INFINITY, vmax = -INFINITY;
    if (p < PP){
        int off[9]; bool val[9];
        tap_setup(p, off, val);
        const float* src = bevs + (size_t)img*64*PP;
        float acc = cb[0];
        for (int c=0;c<64;c++){
            const float* sc = src + (size_t)c*PP;
            const float* wc = &wl[c*9];
#pragma unroll
            for (int t=0;t<9;t++){
                if (val[t]){
                    float v = sc[off[t]];
                    acc = fmaf(wc[t], v, acc);
                    vmin = fminf(vmin, v); vmax = fmaxf(vmax, v);
                }
            }
        }
        com[(size_t)img*PP + p] = fmaxf(acc, 0.0f);
    }
    if (n > 0){
#pragma unroll
        for (int s=32;s>0;s>>=1){
            vmin = fminf(vmin, __shfl_xor(vmin, s, 64));
            vmax = fmaxf(vmax, __shfl_xor(vmax, s, 64));
        }
        if ((threadIdx.x & 63) == 0){
            int im12 = (img/5)*4 + (n-1);
            atomicMin(&misc[im12], f2ord(vmin));
            atomicMax(&misc[12+im12], f2ord(vmax));
        }
    }
}

__global__ __launch_bounds__(256) void k_ent(const float* __restrict__ com,
        float* __restrict__ ent)
{
    int img = blockIdx.y;
    int p = blockIdx.x*256 + threadIdx.x;
    if (p >= PP) return;
    int off[9]; bool val[9];
    tap_setup(p, off, val);
    const float* s = com + (size_t)img*PP;
    float x = s[p];
    float acc = 0.0f;
#pragma unroll
    for (int t=0;t<9;t++){
        float xv = val[t] ? s[off[t]] : 0.0f;   // zero pad
        acc += 1.0f/(1.0f + expf(x - xv));      // sigmoid(xv - x)
    }
    ent[(size_t)img*PP + p] = acc / 9.0f;
}

__global__ __launch_bounds__(256) void k_mask(const float* __restrict__ ent,
        float* __restrict__ maskb, unsigned* __restrict__ misc)
{
    int im12 = blockIdx.y; int bt = im12 >> 2; int n = (im12 & 3) + 1;
    int p = blockIdx.x*256 + threadIdx.x;
    int v = 0;
    if (p < PP){
        float en = ent[(size_t)(bt*5+n)*PP + p];
        float et = ent[(size_t)(bt*5)*PP + p];
        v = en > et;
        maskb[(size_t)im12*PP + p] = (float)v;
    }
    unsigned long long bal = __ballot(v);
    if ((threadIdx.x & 63) == 0) atomicAdd(&misc[24], (unsigned)__popcll(bal));
}

__global__ __launch_bounds__(256) void k_den(const float* __restrict__ maskb,
        float* __restrict__ denb)
{
    int im12 = blockIdx.y;
    int p = blockIdx.x*256 + threadIdx.x;
    if (p >= PP) return;
    int off[9]; bool val[9];
    tap_setup(p, off, val);
    const float* mrow = maskb + (size_t)im12*PP;
    float s = 0.0f;
#pragma unroll
    for (int t=0;t<9;t++) if (val[t]) s += mrow[off[t]];
    denb[(size_t)im12*PP + p] = s;
}

__global__ void k_fin(unsigned* misc, float* bwout){
    int t = threadIdx.x;
    if (t < 12){
        float mn = ord2f(misc[t]);
        float mx = ord2f(misc[12+t]);
        ((int*)misc)[25+t] = (mn + mx == 0.0f) ? 1 : 0;
    }
    if (t == 12) bwout[0] = (float)misc[24] / 480000.0f;
}

#define ACC_FMA128(xc, wbase) do { \
    const float4* _wr = (const float4*)(wbase); \
    _Pragma("unroll") \
    for (int _o4=0;_o4<32;_o4++){ \
        float4 _wv = _wr[_o4]; \
        acc[_o4*4+0] = fmaf(_wv.x, (xc), acc[_o4*4+0]); \
        acc[_o4*4+1] = fmaf(_wv.y, (xc), acc[_o4*4+1]); \
        acc[_o4*4+2] = fmaf(_wv.z, (xc), acc[_o4*4+2]); \
        acc[_o4*4+3] = fmaf(_wv.w, (xc), acc[_o4*4+3]); \
    } \
} while(0)

// n=0 branch: u = W1a@tg + b1 (stored), logit0 = pwf([tg;tg])
__global__ __launch_bounds__(256) void k_pwf0(const float* __restrict__ bevs,
        const float* __restrict__ w1, const float* __restrict__ b1,
        const float* __restrict__ w2, const float* __restrict__ b2,
        const float* __restrict__ w3, const float* __restrict__ b3,
        const float* __restrict__ w4, const float* __restrict__ b4,
        float* __restrict__ ubuf, float* __restrict__ logits)
{
    __shared__ __align__(16) float w1t[64*128];
    __shared__ __align__(16) float w2t[128*32];
    __shared__ __align__(16) float w3t[32*8];
    __shared__ float w4l[8], b1l[128], b2l[32], b3l[8], b4l[1];
    int bt = blockIdx.y;
    int tid = threadIdx.x;
    for (int i=tid;i<64*128;i+=256){ int c=i>>7, o=i&127; w1t[i] = w1[o*128 + c]; }
    for (int i=tid;i<128*32;i+=256){ int o=i>>5, j=i&31; w2t[i] = w2[j*128 + o]; }
    for (int i=tid;i<32*8;i+=256){ int j=i>>3, k=i&7; w3t[i] = w3[k*32 + j]; }
    if (tid<8)   w4l[tid]=w4[tid];
    if (tid<128) b1l[tid]=b1[tid];
    if (tid<32)  b2l[tid]=b2[tid];
    if (tid<8)   b3l[tid]=b3[tid];
    if (tid==0)  b4l[0]=b4[0];
    __syncthreads();
    int p = blockIdx.x*256 + tid;
    float acc[128];
#pragma unroll
    for (int o=0;o<128;o++) acc[o]=0.0f;
    const float* tg = bevs + (size_t)bt*5*64*PP;
    if (p < PP){
        for (int c=0;c<64;c++){
            float xc = tg[(size_t)c*PP + p];
            ACC_FMA128(xc, &w1t[c*128]);
        }
        if (ubuf){
            float* ub = ubuf + (size_t)bt*128*PP + p;
#pragma unroll
            for (int o=0;o<128;o++) ub[(size_t)o*PP] = acc[o] + b1l[o];
        }
    }
    __syncthreads();
    // reload second half: W1b^T
    for (int i=tid;i<64*128;i+=256){ int c=i>>7, o=i&127; w1t[i] = w1[o*128 + 64 + c]; }
    __syncthreads();
    if (p >= PP) return;
    for (int c=0;c<64;c++){
        float xc = tg[(size_t)c*PP + p];
        ACC_FMA128(xc, &w1t[c*128]);
    }
    // layers 2..4
    float z[32];
#pragma unroll
    for (int j=0;j<32;j++) z[j]=b2l[j];
#pragma unroll
    for (int o=0;o<128;o++){
        float v = fmaxf(acc[o]+b1l[o], 0.0f);
        const float4* w2r = (const float4*)&w2t[o*32];
#pragma unroll
        for (int j4=0;j4<8;j4++){
            float4 wv = w2r[j4];
            z[j4*4+0]=fmaf(wv.x,v,z[j4*4+0]);
            z[j4*4+1]=fmaf(wv.y,v,z[j4*4+1]);
            z[j4*4+2]=fmaf(wv.z,v,z[j4*4+2]);
            z[j4*4+3]=fmaf(wv.w,v,z[j4*4+3]);
        }
    }
    float y3[8];
#pragma unroll
    for (int k=0;k<8;k++) y3[k]=b3l[k];
#pragma unroll
    for (int j=0;j<32;j++){
        float v = fmaxf(z[j],0.0f);
#pragma unroll
        for (int k=0;k<8;k++) y3[k] = fmaf(w3t[j*8+k], v, y3[k]);
    }
    float sres = b4l[0];
#pragma unroll
    for (int k=0;k<8;k++) sres = fmaf(w4l[k], fmaxf(y3[k],0.0f), sres);
    logits[(size_t)(bt*5)*PP + p] = fmaxf(sres, 0.0f);
}

// n>=1 branches: warp recomputed inline; MODE 0 reads stored u; MODE 1 recomputes W1a@tg
template<int MODE>
__global__ __launch_bounds__(256) void k_pwfn(const float* __restrict__ bevs,
        const float* __restrict__ w1, const float* __restrict__ b1,
        const float* __restrict__ w2, const float* __restrict__ b2,
        const float* __restrict__ w3, const float* __restrict__ b3,
        const float* __restrict__ w4, const float* __restrict__ b4,
        const float* __restrict__ maskb, const float* __restrict__ denb,
        const float* __restrict__ ubuf, const unsigned* __restrict__ misc,
        float* __restrict__ logits)
{
    __shared__ __align__(16) float w1t[64*128];
    __shared__ __align__(16) float w2t[128*32];
    __shared__ __align__(16) float w3t[32*8];
    __shared__ float w4l[8], b1l[128], b2l[32], b3l[8], b4l[1];
    int tid = threadIdx.x;
    for (int i=tid;i<64*128;i+=256){ int c=i>>7, o=i&127; w1t[i] = w1[o*128 + 64 + c]; }
    for (int i=tid;i<128*32;i+=256){ int o=i>>5, j=i&31; w2t[i] = w2[j*128 + o]; }
    for (int i=tid;i<32*8;i+=256){ int j=i>>3, k=i&7; w3t[i] = w3[k*32 + j]; }
    if (tid<8)   w4l[tid]=w4[tid];
    if (tid<128) b1l[tid]=b1[tid];
    if (tid<32)  b2l[tid]=b2[tid];
    if (tid<8)   b3l[tid]=b3[tid];
    if (tid==0)  b4l[0]=b4[0];
    __syncthreads();
    int im12 = blockIdx.y; int bt = im12 >> 2; int n = (im12 & 3) + 1;
    int p = blockIdx.x*256 + tid;
    float acc[128];
#pragma unroll
    for (int o=0;o<128;o++) acc[o]=0.0f;
    if (p < PP){
        int off[9]; bool val[9];
        tap_setup(p, off, val);
        const float* mrow = maskb + (size_t)im12*PP;
        float m9[9];
#pragma unroll
        for (int t=0;t<9;t++) m9[t] = val[t] ? mrow[off[t]] : 0.0f;
        float rden = 1.0f/(denb[(size_t)im12*PP + p] + NEPS);
        int iz = ((const int*)misc)[25+im12];
        const float* nbb = bevs + (size_t)(bt*5+n)*64*PP;
        for (int c=0;c<64;c++){
            const float* sc = nbb + (size_t)c*PP;
            float num = 0.0f, center = 0.0f;
#pragma unroll
            for (int t=0;t<9;t++){
                if (val[t]){
                    float v = sc[off[t]];
                    num = fmaf(m9[t], v, num);
                    if (t==4) center = v;
                }
            }
            float mc = m9[4];
            float xc = iz ? center : fmaf(mc, center, (1.0f-mc)*(num*rden));
            ACC_FMA128(xc, &w1t[c*128]);
        }
    }
    if (MODE == 1){
        __syncthreads();
        for (int i=tid;i<64*128;i+=256){ int c=i>>7, o=i&127; w1t[i] = w1[o*128 + c]; }
        __syncthreads();
        if (p < PP){
            const float* tgb = bevs + (size_t)bt*5*64*PP;
            for (int c=0;c<64;c++){
                float xc = tgb[(size_t)c*PP + p];
                ACC_FMA128(xc, &w1t[c*128]);
            }
        }
    }
    if (p >= PP) return;
    const float* ub = (MODE==0) ? (ubuf + (size_t)bt*128*PP + p) : nullptr;
    float z[32];
#pragma unroll
    for (int j=0;j<32;j++) z[j]=b2l[j];
#pragma unroll
    for (int o=0;o<128;o++){
        float pre = (MODE==0) ? (acc[o] + ub[(size_t)o*PP]) : (acc[o] + b1l[o]);
        float v = fmaxf(pre, 0.0f);
        const float4* w2r = (const float4*)&w2t[o*32];
#pragma unroll
        for (int j4=0;j4<8;j4++){
            float4 wv = w2r[j4];
            z[j4*4+0]=fmaf(wv.x,v,z[j4*4+0]);
            z[j4*4+1]=fmaf(wv.y,v,z[j4*4+1]);
            z[j4*4+2]=fmaf(wv.z,v,z[j4*4+2]);
            z[j4*4+3]=fmaf(wv.w,v,z[j4*4+3]);
        }
    }
    float y3[8];
#pragma unroll
    for (int k=0;k<8;k++) y3[k]=b3l[k];
#pragma unroll
    for (int j=0;j<32;j++){
        float v = fmaxf(z[j],0.0f);
#pragma unroll
        for (int k=0;k<8;k++) y3[k] = fmaf(w3t[j*8+k], v, y3[k]);
    }
    float sres = b4l[0];
#pragma unroll
    for (int k=0;k<8;k++) sres = fmaf(w4l[k], fmaxf(y3[k],0.0f), sres);
    logits[(size_t)(bt*5+n)*PP + p] = fmaxf(sres, 0.0f);
}

__global__ __launch_bounds__(256) void k_fuse(const float* __restrict__ bevs,
        const float* __restrict__ logits, const float* __restrict__ maskb,
        const float* __restrict__ denb, const unsigned* __restrict__ misc,
        float* __restrict__ out)
{
    int bt = blockIdx.y;
    int p = blockIdx.x*256 + threadIdx.x;
    if (p >= PP) return;
    int off[9]; bool val[9];
    tap_setup(p, off, val);
    float e[5], ssum = 0.0f;
#pragma unroll
    for (int nn=0;nn<5;nn++){ e[nn] = expf(logits[(size_t)(bt*5+nn)*PP + p]); ssum += e[nn]; }
    float wts[5];
#pragma unroll
    for (int nn=0;nn<5;nn++) wts[nn] = e[nn] / ssum;
    float m9[4][9]; float rden[4]; int iz[4];
#pragma unroll
    for (int k=0;k<4;k++){
        int im12 = bt*4 + k;
        const float* mrow = maskb + (size_t)im12*PP;
#pragma unroll
        for (int t=0;t<9;t++) m9[k][t] = val[t] ? mrow[off[t]] : 0.0f;
        rden[k] = 1.0f/(denb[(size_t)im12*PP + p] + NEPS);
        iz[k] = ((const int*)misc)[25+im12];
    }
    const float* base = bevs + (size_t)bt*5*64*PP;
    for (int c=0;c<64;c++){
        float tgc = base[(size_t)c*PP + p];
        float fused = wts[0]*tgc;
#pragma unroll
        for (int k=0;k<4;k++){
            const float* sc = base + (size_t)(k+1)*64*PP + (size_t)c*PP;
            float num = 0.0f, center = 0.0f;
#pragma unroll
            for (int t=0;t<9;t++){
                if (val[t]){
                    float v = sc[off[t]];
                    num = fmaf(m9[k][t], v, num);
                    if (t==4) center = v;
                }
            }
            float mc = m9[k][4];
            float xc = iz[k] ? center : fmaf(mc, center, (1.0f-mc)*(num*rden[k]));
            fused = fmaf(wts[k+1], xc, fused);
        }
        out[((size_t)bt*64 + c)*PP + p] = fused;
    }
}

extern "C" void kernel_launch(void* const* d_in, const int* in_sizes, int n_in,
                              void* d_out, int out_size, void* d_ws, size_t ws_size,
                              hipStream_t stream)
{
    const float* bevs = (const float*)d_in[0];
    const float* cw  = (const float*)d_in[1];
    const float* cb  = (const float*)d_in[2];
    const float* w1  = (const float*)d_in[3];
    const float* b1  = (const float*)d_in[4];
    const float* w2  = (const float*)d_in[5];
    const float* b2  = (const float*)d_in[6];
    const float* w3  = (const float*)d_in[7];
    const float* b3  = (const float*)d_in[8];
    const float* w4  = (const float*)d_in[9];
    const float* b4  = (const float*)d_in[10];
    float* out = (float*)d_out;
    float* ws = (float*)d_ws;

    bool useU = ws_size >= (size_t)(MISC_FULL + 64) * 4;
    float* com    = ws + OFF_COM;
    float* ent    = ws + OFF_ENT;
    float* maskb  = ws + OFF_MASK;
    float* denb   = ws + OFF_DEN;
    float* logits = ws + OFF_LOGITS;
    float* ubuf   = useU ? (ws + OFF_U) : nullptr;
    unsigned* misc = (unsigned*)(ws + (useU ? MISC_FULL : MISC_MIN));

    dim3 blk(256,1,1);
    int gx = (PP + 255)/256;

    k_init<<<dim3(1),dim3(64),0,stream>>>(misc);
    k_conv<<<dim3(gx,15),blk,0,stream>>>(bevs,cw,cb,com,misc);
    k_ent <<<dim3(gx,15),blk,0,stream>>>(com,ent);
    k_mask<<<dim3(gx,12),blk,0,stream>>>(ent,maskb,misc);
    k_den <<<dim3(gx,12),blk,0,stream>>>(maskb,denb);
    k_fin <<<dim3(1),dim3(64),0,stream>>>(misc, out + (size_t)3*64*PP);
    k_pwf0<<<dim3(gx,3),blk,0,stream>>>(bevs,w1,b1,w2,b2,w3,b3,w4,b4,ubuf,logits);
    if (useU)
        k_pwfn<0><<<dim3(gx,12),blk,0,stream>>>(bevs,w1,b1,w2,b2,w3,b3,w4,b4,maskb,denb,ubuf,misc,logits);
    else
        k_pwfn<1><<<dim3(gx,12),blk,0,stream>>>(bevs,w1,b1,w2,b2,w3,b3,w4,b4,maskb,denb,ubuf,misc,logits);
    k_fuse<<<dim3(gx,3),blk,0,stream>>>(bevs,logits,maskb,denb,misc,out);
}